// Round 1
// baseline (142.738 us; speedup 1.0000x reference)
//
#include <hip/hip_runtime.h>
#include <math.h>

#define NUM_EMB 256
#define EMB_DIM 64
#define KSEL 4
#define NBINS 33
#define NSIG 32768      // B*H*W = 32*32*32
#define NBLK (NSIG/4)   // 8192 blocks, 4 signals each

// ws layout (bytes):
//   Dn    float [64*256]    @ 0        (65536 B)
//   G     float [256*256]   @ 65536    (262144 B)
//   part  double[NBLK]      @ 327680   (65536 B)

__global__ void norm_kernel(const float* __restrict__ dict, float* __restrict__ Dn) {
    int a = threadIdx.x; // 0..255, one atom per thread
    double s = 0.0;
    for (int c = 0; c < EMB_DIM; ++c) {
        double v = (double)dict[c * NUM_EMB + a];
        s += v * v;
    }
    double inv = 1.0 / fmax(sqrt(s), 1e-10);
    for (int c = 0; c < EMB_DIM; ++c)
        Dn[c * NUM_EMB + a] = (float)((double)dict[c * NUM_EMB + a] * inv);
}

__global__ void gram_kernel(const float* __restrict__ Dn, float* __restrict__ G) {
    __shared__ float ca[EMB_DIM];
    int a = blockIdx.x;   // row of G
    int l = threadIdx.x;  // 0..63
    ca[l] = Dn[l * NUM_EMB + a];
    __syncthreads();
    #pragma unroll
    for (int j = 0; j < 4; ++j) {
        int b = l + 64 * j;
        double s = 0.0;
        for (int c = 0; c < EMB_DIM; ++c)
            s += (double)ca[c] * (double)Dn[c * NUM_EMB + b];
        G[a * NUM_EMB + b] = (float)s;
    }
}

__global__ __launch_bounds__(256)
void omp_kernel(const float* __restrict__ z_e, const float* __restrict__ Dn,
                const float* __restrict__ G, float* __restrict__ out,
                double* __restrict__ partial) {
    __shared__ double zs[4][EMB_DIM];
    __shared__ double hb[4][NUM_EMB];
    __shared__ double wsum[4];
    const int t = threadIdx.x;
    const int w = t >> 6, l = t & 63;
    const int n0 = blockIdx.x * 4;

    // ---- phase 1: load 4 signals (lane = channel) ----
    {
        int n = n0 + w;
        int b = n >> 10, hw = n & 1023;
        zs[w][l] = (double)z_e[((b * EMB_DIM + l) << 10) + hw];
    }
    __syncthreads();

    // ---- phase 2: h_bar = Dn^T x, block-cooperative (thread t owns atom t) ----
    {
        double a0 = 0, a1 = 0, a2 = 0, a3 = 0;
        for (int c = 0; c < EMB_DIM; ++c) {
            double dn = (double)Dn[c * NUM_EMB + t];   // coalesced across t
            a0 += dn * zs[0][c];
            a1 += dn * zs[1][c];
            a2 += dn * zs[2][c];
            a3 += dn * zs[3][c];
        }
        hb[0][t] = a0; hb[1][t] = a1; hb[2][t] = a2; hb[3][t] = a3;
    }
    __syncthreads();

    // ---- phase 3: per-wave OMP (wave w -> signal n0+w), lane owns atoms l+64j ----
    const int n = n0 + w;
    int I[KSEL];
    double Lm[KSEL][KSEL];
    double hI[KSEL];
    double x[KSEL];
    int selbits = 0;

    #pragma unroll
    for (int k = 0; k < KSEL; ++k) {
        // candidate per owned atom: |h| with selected atoms competing as 0.0
        double bv = -1.0; int bi = 0;
        #pragma unroll
        for (int j = 0; j < 4; ++j) {
            int a = l + 64 * j;
            double v;
            if ((selbits >> j) & 1) {
                v = 0.0;
            } else {
                double h = hb[w][a];
                #pragma unroll
                for (int m = 0; m < k; ++m)
                    h -= x[m] * (double)G[I[m] * NUM_EMB + a];
                v = fabs(h);
            }
            if (v > bv) { bv = v; bi = a; }   // increasing a: keeps first max
        }
        // wave argmax, tie -> smaller index (matches jnp.argmax first-occurrence)
        #pragma unroll
        for (int off = 1; off < 64; off <<= 1) {
            double ov = __shfl_xor(bv, off);
            int    oi = __shfl_xor(bi, off);
            if (ov > bv || (ov == bv && oi < bi)) { bv = ov; bi = oi; }
        }
        if ((bi & 63) == l) selbits |= 1 << (bi >> 6);

        // incremental Cholesky update
        if (k == 0) {
            Lm[0][0] = 1.0;
        } else {
            double gs[KSEL], wv[KSEL], s2 = 0.0;
            #pragma unroll
            for (int j = 0; j < k; ++j) gs[j] = (double)G[I[j] * NUM_EMB + bi];
            #pragma unroll
            for (int i = 0; i < k; ++i) {
                double v = gs[i];
                #pragma unroll
                for (int j = 0; j < i; ++j) v -= Lm[i][j] * wv[j];
                v /= Lm[i][i];
                wv[i] = v;
                s2 += v * v;
            }
            #pragma unroll
            for (int j = 0; j < k; ++j) Lm[k][j] = wv[j];
            Lm[k][k] = sqrt(fmax(1.0 - s2, 1e-12));
        }
        I[k]  = bi;
        hI[k] = hb[w][bi];

        // solve L L^T x = h_bar[I]  (size k+1)
        double y[KSEL];
        #pragma unroll
        for (int i = 0; i <= k; ++i) {
            double v = hI[i];
            #pragma unroll
            for (int j = 0; j < i; ++j) v -= Lm[i][j] * y[j];
            y[i] = v / Lm[i][i];
        }
        #pragma unroll
        for (int i = k; i >= 0; --i) {
            double v = y[i];
            #pragma unroll
            for (int j = i + 1; j <= k; ++j) v -= Lm[j][i] * x[j];
            x[i] = v / Lm[i][i];
        }
    }

    // ---- phase 4: quantize (fp32, matching jnp semantics), tokens, recon, loss ----
    float cq[KSEL]; int tok[KSEL];
    #pragma unroll
    for (int i = 0; i < KSEL; ++i) {
        float xf = (float)x[i];
        float c  = fminf(fmaxf(xf, -2.0f), 2.0f);
        float binf = ((c + 2.0f) / 4.0f) * 32.0f;
        int bin = (int)rintf(binf);              // half-to-even, like jnp.round
        bin = bin < 0 ? 0 : (bin > 32 ? 32 : bin);
        cq[i]  = -2.0f + 0.125f * (float)bin;    // CENTERS[bin], exact
        tok[i] = I[i] * NBINS + bin;
    }
    if (l < KSEL)
        out[NSIG * EMB_DIM + 1 + n * KSEL + l] = (float)tok[l];

    double zq = 0.0;
    #pragma unroll
    for (int i = 0; i < KSEL; ++i)
        zq += (double)cq[i] * (double)Dn[l * NUM_EMB + I[i]];
    float zqf = (float)zq;
    int b = n >> 10, hw = n & 1023;
    out[((b * EMB_DIM + l) << 10) + hw] = zqf;

    double d = (double)zqf - zs[w][l];
    double sq = d * d;
    #pragma unroll
    for (int off = 1; off < 64; off <<= 1)
        sq += __shfl_xor(sq, off);
    if (l == 0) wsum[w] = sq;
    __syncthreads();
    if (t == 0) partial[blockIdx.x] = wsum[0] + wsum[1] + wsum[2] + wsum[3];
}

__global__ void loss_kernel(const double* __restrict__ partial, float* __restrict__ out) {
    __shared__ double sh[256];
    int t = threadIdx.x;
    double s = 0.0;
    for (int i = t; i < NBLK; i += 256) s += partial[i];
    sh[t] = s;
    __syncthreads();
    for (int off = 128; off > 0; off >>= 1) {
        if (t < off) sh[t] += sh[t + off];
        __syncthreads();
    }
    if (t == 0)
        out[NSIG * EMB_DIM] = (float)(1.25 * sh[0] / (double)(NSIG * EMB_DIM));
}

extern "C" void kernel_launch(void* const* d_in, const int* in_sizes, int n_in,
                              void* d_out, int out_size, void* d_ws, size_t ws_size,
                              hipStream_t stream) {
    const float* z_e  = (const float*)d_in[0];
    const float* dict = (const float*)d_in[1];
    float* out = (float*)d_out;

    float*  Dn      = (float*)d_ws;
    float*  G       = (float*)((char*)d_ws + 65536);
    double* partial = (double*)((char*)d_ws + 327680);

    norm_kernel<<<1, 256, 0, stream>>>(dict, Dn);
    gram_kernel<<<NUM_EMB, 64, 0, stream>>>(Dn, G);
    omp_kernel<<<NBLK, 256, 0, stream>>>(z_e, Dn, G, out, partial);
    loss_kernel<<<1, 256, 0, stream>>>(partial, out);
}

// Round 2
// 90.219 us; speedup vs baseline: 1.5821x; 1.5821x over previous
//
#include <hip/hip_runtime.h>
#include <math.h>

#define NUM_EMB 256
#define EMB_DIM 64
#define KSEL 4
#define NBINS 33
#define NSIG 32768          // B*H*W = 32*32*32
#define SPB 16              // signals per block (4 waves x 4 signals/wave)
#define NBLK (NSIG / SPB)   // 2048 blocks

// ws layout (bytes):
//   Dn      float [64*256]     @ 0        (65536 B)
//   G       float [256*256]    @ 65536    (262144 B)
//   partial double[NBLK*4]     @ 327680   (65536 B)

__global__ void norm_kernel(const float* __restrict__ dict, float* __restrict__ Dn) {
    int a = threadIdx.x; // one atom per thread
    double s = 0.0;
    #pragma unroll 8
    for (int c = 0; c < EMB_DIM; ++c) {
        double v = (double)dict[c * NUM_EMB + a];
        s += v * v;
    }
    double inv = 1.0 / fmax(sqrt(s), 1e-10);
    #pragma unroll 8
    for (int c = 0; c < EMB_DIM; ++c)
        Dn[c * NUM_EMB + a] = (float)((double)dict[c * NUM_EMB + a] * inv);
}

__global__ void gram_kernel(const float* __restrict__ Dn, float* __restrict__ G) {
    __shared__ float ca[EMB_DIM];
    int a = blockIdx.x;   // row of G
    int t = threadIdx.x;  // column (one dot per thread)
    if (t < EMB_DIM) ca[t] = Dn[t * NUM_EMB + a];
    __syncthreads();
    double s = 0.0;
    #pragma unroll 8
    for (int c = 0; c < EMB_DIM; ++c)
        s += (double)ca[c] * (double)Dn[c * NUM_EMB + t];
    G[a * NUM_EMB + t] = (float)s;
}

// Block: 256 threads = 4 waves; wave w handles signals n0..n0+3 independently.
// Within a wave, 16-lane group g owns signal n0+g for the OMP solve phase.
// Per-wave private LDS slice (1024 doubles): first used as zs[4][64]
// (signal-major z staging), then aliased as hb[4][256] (h_bar per signal).
__global__ __launch_bounds__(256, 4)
void omp_kernel(const float* __restrict__ z_e, const float* __restrict__ Dn,
                const float* __restrict__ G, float* __restrict__ out,
                double* __restrict__ partial) {
    __shared__ double sbuf[4][1024];
    const int t = threadIdx.x;
    const int w = t >> 6, l = t & 63;
    const int g = l >> 4, li = l & 15;
    const int n0 = blockIdx.x * SPB + w * 4;   // wave's first signal
    double* sb = sbuf[w];

    // ---- phase 1: stage 4 signals, lane = channel ----
    #pragma unroll
    for (int s = 0; s < 4; ++s) {
        int n = n0 + s, b = n >> 10, hw = n & 1023;
        sb[s * EMB_DIM + l] = (double)z_e[((b * EMB_DIM + l) << 10) + hw];
    }
    asm volatile("s_waitcnt lgkmcnt(0)" ::: "memory"); // writes visible wave-wide

    // ---- phase 2: h_bar = Dn^T x for 4 signals; lane owns atoms l+64*jj ----
    double acc[4][4]; // [signal][jj]
    #pragma unroll
    for (int s = 0; s < 4; ++s)
        #pragma unroll
        for (int j = 0; j < 4; ++j) acc[s][j] = 0.0;

    #pragma unroll 4
    for (int c = 0; c < EMB_DIM; ++c) {
        const float* dp = Dn + c * NUM_EMB + l;
        double d0 = (double)dp[0];
        double d1 = (double)dp[64];
        double d2 = (double)dp[128];
        double d3 = (double)dp[192];
        double z0 = sb[c], z1 = sb[EMB_DIM + c], z2 = sb[2 * EMB_DIM + c], z3 = sb[3 * EMB_DIM + c];
        acc[0][0] += d0 * z0; acc[0][1] += d1 * z0; acc[0][2] += d2 * z0; acc[0][3] += d3 * z0;
        acc[1][0] += d0 * z1; acc[1][1] += d1 * z1; acc[1][2] += d2 * z1; acc[1][3] += d3 * z1;
        acc[2][0] += d0 * z2; acc[2][1] += d1 * z2; acc[2][2] += d2 * z2; acc[2][3] += d3 * z2;
        acc[3][0] += d0 * z3; acc[3][1] += d1 * z3; acc[3][2] += d2 * z3; acc[3][3] += d3 * z3;
    }
    asm volatile("s_waitcnt lgkmcnt(0)" ::: "memory"); // all zs reads retired
    // remap to hb[s][a] at sb[s*256 + a] (aliases zs region; safe after wait)
    #pragma unroll
    for (int s = 0; s < 4; ++s)
        #pragma unroll
        for (int j = 0; j < 4; ++j)
            sb[s * NUM_EMB + l + 64 * j] = acc[s][j];
    asm volatile("s_waitcnt lgkmcnt(0)" ::: "memory"); // hb visible wave-wide

    // ---- phase 3: OMP, group g -> signal n0+g; lane owns atoms li+16*j ----
    const double* hb = sb + g * NUM_EMB;
    int I[KSEL];
    double Lm[KSEL][KSEL], rL[KSEL], hI[KSEL], x[KSEL];
    unsigned selbits = 0;

    #pragma unroll
    for (int k = 0; k < KSEL; ++k) {
        // candidate per owned atom: |h| with selected atoms competing as 0.0
        double bv = -1.0; int bi = 0;
        #pragma unroll
        for (int j = 0; j < 16; ++j) {
            int a = li + 16 * j;
            double h = hb[a];
            #pragma unroll
            for (int m = 0; m < k; ++m)
                h -= x[m] * (double)G[(I[m] << 8) + a];
            double v = ((selbits >> j) & 1u) ? 0.0 : fabs(h);
            if (v > bv) { bv = v; bi = a; }   // ascending a: keeps first max
        }
        // 16-lane group argmax, tie -> smaller index (jnp.argmax semantics)
        #pragma unroll
        for (int off = 1; off < 16; off <<= 1) {
            double ov = __shfl_xor(bv, off);
            int    oi = __shfl_xor(bi, off);
            if (ov > bv || (ov == bv && oi < bi)) { bv = ov; bi = oi; }
        }
        if ((bi & 15) == li) selbits |= 1u << (bi >> 4);

        // incremental Cholesky (reciprocal diag cached in rL)
        if (k == 0) {
            Lm[0][0] = 1.0; rL[0] = 1.0;
        } else {
            double wv[KSEL], s2 = 0.0;
            #pragma unroll
            for (int i = 0; i < k; ++i) {
                double v = (double)G[(I[i] << 8) + bi];
                #pragma unroll
                for (int j2 = 0; j2 < i; ++j2) v -= Lm[i][j2] * wv[j2];
                v *= rL[i];
                wv[i] = v; s2 += v * v;
            }
            #pragma unroll
            for (int j2 = 0; j2 < k; ++j2) Lm[k][j2] = wv[j2];
            double dg = sqrt(fmax(1.0 - s2, 1e-12));
            Lm[k][k] = dg; rL[k] = 1.0 / dg;
        }
        I[k]  = bi;
        hI[k] = hb[bi];

        // solve L L^T x = h_bar[I]  (size k+1)
        double y[KSEL];
        #pragma unroll
        for (int i = 0; i <= k; ++i) {
            double v = hI[i];
            #pragma unroll
            for (int j2 = 0; j2 < i; ++j2) v -= Lm[i][j2] * y[j2];
            y[i] = v * rL[i];
        }
        #pragma unroll
        for (int i = k; i >= 0; --i) {
            double v = y[i];
            #pragma unroll
            for (int j2 = i + 1; j2 <= k; ++j2) v -= Lm[j2][i] * x[j2];
            x[i] = v * rL[i];
        }
    }

    // ---- phase 4: quantize (fp32, jnp semantics) + tokens ----
    float cq[KSEL]; int tok[KSEL];
    #pragma unroll
    for (int i = 0; i < KSEL; ++i) {
        float xf = (float)x[i];
        float cc = fminf(fmaxf(xf, -2.0f), 2.0f);
        int bin = (int)rintf((cc + 2.0f) * 8.0f);  // == (c+2)/4*32, pow2-exact
        bin = bin < 0 ? 0 : (bin > 32 ? 32 : bin);
        cq[i]  = -2.0f + 0.125f * (float)bin;      // CENTERS[bin], exact
        tok[i] = I[i] * NBINS + bin;
    }
    if (li < KSEL) {
        float tv = li == 0 ? (float)tok[0]
                 : li == 1 ? (float)tok[1]
                 : li == 2 ? (float)tok[2] : (float)tok[3];
        out[NSIG * EMB_DIM + 1 + (n0 + g) * KSEL + li] = tv;
    }

    // ---- phase 5: reconstruction (lane = channel) + loss partial ----
    double sq = 0.0;
    #pragma unroll
    for (int s = 0; s < 4; ++s) {
        double z = 0.0;
        #pragma unroll
        for (int i = 0; i < KSEL; ++i) {
            int   Iv  = __shfl(I[i],  s * 16);   // broadcast from group s
            float cqv = __shfl(cq[i], s * 16);
            z += (double)cqv * (double)Dn[(l << 8) + Iv];
        }
        float zf = (float)z;
        int n = n0 + s, b = n >> 10, hw = n & 1023;
        int idx = ((b * EMB_DIM + l) << 10) + hw;
        out[idx] = zf;
        double d = (double)zf - (double)z_e[idx];  // z_e re-read (L2-hot)
        sq += d * d;
    }
    #pragma unroll
    for (int off = 1; off < 64; off <<= 1)
        sq += __shfl_xor(sq, off);
    if (l == 0) partial[blockIdx.x * 4 + w] = sq;
}

__global__ void loss_kernel(const double* __restrict__ partial, float* __restrict__ out) {
    __shared__ double sh[256];
    int t = threadIdx.x;
    double s = 0.0;
    for (int i = t; i < NBLK * 4; i += 256) s += partial[i];
    sh[t] = s;
    __syncthreads();
    for (int off = 128; off > 0; off >>= 1) {
        if (t < off) sh[t] += sh[t + off];
        __syncthreads();
    }
    if (t == 0)
        out[NSIG * EMB_DIM] = (float)(1.25 * sh[0] / (double)(NSIG * EMB_DIM));
}

extern "C" void kernel_launch(void* const* d_in, const int* in_sizes, int n_in,
                              void* d_out, int out_size, void* d_ws, size_t ws_size,
                              hipStream_t stream) {
    const float* z_e  = (const float*)d_in[0];
    const float* dict = (const float*)d_in[1];
    float* out = (float*)d_out;

    float*  Dn      = (float*)d_ws;
    float*  G       = (float*)((char*)d_ws + 65536);
    double* partial = (double*)((char*)d_ws + 327680);

    norm_kernel<<<1, 256, 0, stream>>>(dict, Dn);
    gram_kernel<<<NUM_EMB, 256, 0, stream>>>(Dn, G);
    omp_kernel<<<NBLK, 256, 0, stream>>>(z_e, Dn, G, out, partial);
    loss_kernel<<<1, 256, 0, stream>>>(partial, out);
}

// Round 3
// 80.011 us; speedup vs baseline: 1.7840x; 1.1276x over previous
//
#include <hip/hip_runtime.h>
#include <math.h>

#define NUM_EMB 256
#define EMB_DIM 64
#define KSEL 4
#define NBINS 33
#define NSIG 32768          // B*H*W
#define SPB 16              // signals per block (4 waves x 4 signals/wave)
#define NBLK (NSIG / SPB)   // 2048 blocks

// ws layout (bytes):
//   Dn      float [64][256]   @ 0        (65536)
//   G       float [256][256]  @ 65536    (262144)
//   DnT     float [256][64]   @ 327680   (65536)
//   partial double[NBLK*4]    @ 393216   (65536)

__global__ void norm_kernel(const float* __restrict__ dict, float* __restrict__ Dn,
                            float* __restrict__ DnT) {
    int a = threadIdx.x; // one atom per thread
    double s = 0.0;
    #pragma unroll 8
    for (int c = 0; c < EMB_DIM; ++c) {
        double v = (double)dict[c * NUM_EMB + a];
        s += v * v;
    }
    double inv = 1.0 / fmax(sqrt(s), 1e-10);
    #pragma unroll 8
    for (int c = 0; c < EMB_DIM; ++c) {
        float v = (float)((double)dict[c * NUM_EMB + a] * inv);
        Dn[c * NUM_EMB + a] = v;
        DnT[a * EMB_DIM + c] = v;
    }
}

__global__ void gram_kernel(const float* __restrict__ Dn, float* __restrict__ G) {
    __shared__ float ca[EMB_DIM];
    int a = blockIdx.x;   // row of G
    int t = threadIdx.x;  // column (one dot per thread)
    if (t < EMB_DIM) ca[t] = Dn[t * NUM_EMB + a];
    __syncthreads();
    double s = 0.0;
    #pragma unroll 8
    for (int c = 0; c < EMB_DIM; ++c)
        s += (double)ca[c] * (double)Dn[c * NUM_EMB + t];
    G[a * NUM_EMB + t] = (float)s;
}

// 256 threads = 4 independent waves; wave handles 4 signals.
// Phase 2: lane l owns atoms 4l..4l+3 (coalesced dwordx4 Dn rows).
// Phase 3: 16-lane group g owns signal n0+g; lane li owns atoms 16li..16li+15
// (h_bar held in registers, moved there by a fixed shuffle permutation).
__global__ __launch_bounds__(256, 4)
void omp_kernel(const float* __restrict__ z_e, const float* __restrict__ Dn,
                const float* __restrict__ G, const float* __restrict__ DnT,
                float* __restrict__ out, double* __restrict__ partial) {
    __shared__ double zs[4][4][EMB_DIM];   // [wave][signal][channel]
    const int t = threadIdx.x;
    const int w = t >> 6, l = t & 63;
    const int g = l >> 4, li = l & 15;
    const int n0 = blockIdx.x * SPB + w * 4;
    const int b = n0 >> 10, hw0 = n0 & 1023;   // n0 % 4 == 0, same b for 4 signals

    // ---- phase 1: one float4 load: channel=l, signals n0..n0+3 ----
    const float4 zv = *(const float4*)(z_e + (((b * EMB_DIM + l) << 10) + hw0));
    zs[w][0][l] = (double)zv.x;
    zs[w][1][l] = (double)zv.y;
    zs[w][2][l] = (double)zv.z;
    zs[w][3][l] = (double)zv.w;
    asm volatile("s_waitcnt lgkmcnt(0)" ::: "memory"); // wave-wide visibility

    // ---- phase 2: acc[s][r] = h_bar_s[4l+r], fp64 ----
    double acc[4][4];
    #pragma unroll
    for (int s = 0; s < 4; ++s)
        #pragma unroll
        for (int r = 0; r < 4; ++r) acc[s][r] = 0.0;

    #pragma unroll 4
    for (int c = 0; c < EMB_DIM; c += 2) {
        const float4 dA = *(const float4*)(Dn + c * NUM_EMB + 4 * l);
        const float4 dB = *(const float4*)(Dn + (c + 1) * NUM_EMB + 4 * l);
        double a0 = (double)dA.x, a1 = (double)dA.y, a2 = (double)dA.z, a3 = (double)dA.w;
        double b0 = (double)dB.x, b1 = (double)dB.y, b2 = (double)dB.z, b3 = (double)dB.w;
        #pragma unroll
        for (int s = 0; s < 4; ++s) {
            double2 zp = *(const double2*)&zs[w][s][c];
            acc[s][0] += a0 * zp.x; acc[s][1] += a1 * zp.x;
            acc[s][2] += a2 * zp.x; acc[s][3] += a3 * zp.x;
            acc[s][0] += b0 * zp.y; acc[s][1] += b1 * zp.y;
            acc[s][2] += b2 * zp.y; acc[s][3] += b3 * zp.y;
        }
    }

    // ---- phase 2.5: transpose to phase-3 ownership via shuffles ----
    // hbar[j] (lane (g,li)) = h_bar_{n0+g}[16li+j]; source lane 4li+(j>>2), reg j&3
    double hbar[16];
    #pragma unroll
    for (int j = 0; j < 16; ++j) {
        int src = 4 * li + (j >> 2);
        double t0 = __shfl(acc[0][j & 3], src);
        double t1 = __shfl(acc[1][j & 3], src);
        double t2 = __shfl(acc[2][j & 3], src);
        double t3 = __shfl(acc[3][j & 3], src);
        hbar[j] = (g < 2) ? (g == 0 ? t0 : t1) : (g == 2 ? t2 : t3);
    }

    // ---- phase 3: OMP, group g -> signal n0+g ----
    int I[KSEL];
    double Lm[KSEL][KSEL], rL[KSEL], hI[KSEL], x[KSEL];
    unsigned selbits = 0;

    #pragma unroll
    for (int k = 0; k < KSEL; ++k) {
        double bv = -1.0, bh = 0.0; int bi = 0;
        // scan owned atoms in 4 blocks of 4 (float4 G-row correction loads)
        #pragma unroll
        for (int jb = 0; jb < 4; ++jb) {
            double h0, h1, h2, h3;
            h0 = hbar[4 * jb + 0]; h1 = hbar[4 * jb + 1];
            h2 = hbar[4 * jb + 2]; h3 = hbar[4 * jb + 3];
            #pragma unroll
            for (int m = 0; m < k; ++m) {
                const float4 gv = *(const float4*)(G + (I[m] << 8) + 16 * li + 4 * jb);
                h0 -= x[m] * (double)gv.x;
                h1 -= x[m] * (double)gv.y;
                h2 -= x[m] * (double)gv.z;
                h3 -= x[m] * (double)gv.w;
            }
            #pragma unroll
            for (int r = 0; r < 4; ++r) {
                int j = 4 * jb + r;
                double h = r == 0 ? h0 : r == 1 ? h1 : r == 2 ? h2 : h3;
                double v = ((selbits >> j) & 1u) ? 0.0 : fabs(h);
                if (v > bv) { bv = v; bi = 16 * li + j; bh = hbar[j]; }
            }
        }
        // group argmax, tie -> smaller index (jnp.argmax first-occurrence)
        #pragma unroll
        for (int off = 1; off < 16; off <<= 1) {
            double ov = __shfl_xor(bv, off);
            int    oi = __shfl_xor(bi, off);
            double oh = __shfl_xor(bh, off);
            if (ov > bv || (ov == bv && oi < bi)) { bv = ov; bi = oi; bh = oh; }
        }
        if ((bi >> 4) == li) selbits |= 1u << (bi & 15);

        // incremental Cholesky (reciprocal diagonals cached)
        if (k == 0) {
            Lm[0][0] = 1.0; rL[0] = 1.0;
        } else {
            double wv[KSEL], s2 = 0.0;
            #pragma unroll
            for (int i = 0; i < k; ++i) {
                double v = (double)G[(I[i] << 8) + bi];
                #pragma unroll
                for (int j2 = 0; j2 < i; ++j2) v -= Lm[i][j2] * wv[j2];
                v *= rL[i];
                wv[i] = v; s2 += v * v;
            }
            #pragma unroll
            for (int j2 = 0; j2 < k; ++j2) Lm[k][j2] = wv[j2];
            double dg = sqrt(fmax(1.0 - s2, 1e-12));
            Lm[k][k] = dg; rL[k] = 1.0 / dg;
        }
        I[k]  = bi;
        hI[k] = bh;

        // solve L L^T x = h_bar[I]  (size k+1)
        double y[KSEL];
        #pragma unroll
        for (int i = 0; i <= k; ++i) {
            double v = hI[i];
            #pragma unroll
            for (int j2 = 0; j2 < i; ++j2) v -= Lm[i][j2] * y[j2];
            y[i] = v * rL[i];
        }
        #pragma unroll
        for (int i = k; i >= 0; --i) {
            double v = y[i];
            #pragma unroll
            for (int j2 = i + 1; j2 <= k; ++j2) v -= Lm[j2][i] * x[j2];
            x[i] = v * rL[i];
        }
    }

    // ---- phase 4: quantize (fp32, jnp semantics) + tokens ----
    float cq[KSEL]; int tok[KSEL];
    #pragma unroll
    for (int i = 0; i < KSEL; ++i) {
        float xf = (float)x[i];
        float cc = fminf(fmaxf(xf, -2.0f), 2.0f);
        int bin = (int)rintf((cc + 2.0f) * 8.0f);   // half-to-even, pow2-exact
        bin = bin < 0 ? 0 : (bin > 32 ? 32 : bin);
        cq[i]  = -2.0f + 0.125f * (float)bin;       // CENTERS[bin] exact
        tok[i] = I[i] * NBINS + bin;
    }
    if (li < KSEL) {
        float tv = li == 0 ? (float)tok[0]
                 : li == 1 ? (float)tok[1]
                 : li == 2 ? (float)tok[2] : (float)tok[3];
        out[NSIG * EMB_DIM + 1 + (n0 + g) * KSEL + li] = tv;
    }

    // ---- phase 5: reconstruction (lane=channel, DnT coalesced) + loss ----
    double zq0 = 0.0, zq1 = 0.0, zq2 = 0.0, zq3 = 0.0;
    #pragma unroll
    for (int i = 0; i < KSEL; ++i) {
        int   I0 = __shfl(I[i],  0), I1 = __shfl(I[i], 16);
        int   I2 = __shfl(I[i], 32), I3 = __shfl(I[i], 48);
        float c0 = __shfl(cq[i], 0), c1 = __shfl(cq[i], 16);
        float c2 = __shfl(cq[i], 32), c3 = __shfl(cq[i], 48);
        zq0 += (double)c0 * (double)DnT[(I0 << 6) + l];
        zq1 += (double)c1 * (double)DnT[(I1 << 6) + l];
        zq2 += (double)c2 * (double)DnT[(I2 << 6) + l];
        zq3 += (double)c3 * (double)DnT[(I3 << 6) + l];
    }
    float4 zqv = make_float4((float)zq0, (float)zq1, (float)zq2, (float)zq3);
    *(float4*)(out + (((b * EMB_DIM + l) << 10) + hw0)) = zqv;

    double d0 = (double)zqv.x - zs[w][0][l];
    double d1 = (double)zqv.y - zs[w][1][l];
    double d2 = (double)zqv.z - zs[w][2][l];
    double d3 = (double)zqv.w - zs[w][3][l];
    double sq = d0 * d0 + d1 * d1 + d2 * d2 + d3 * d3;
    #pragma unroll
    for (int off = 1; off < 64; off <<= 1)
        sq += __shfl_xor(sq, off);
    if (l == 0) partial[blockIdx.x * 4 + w] = sq;
}

__global__ void loss_kernel(const double* __restrict__ partial, float* __restrict__ out) {
    __shared__ double sh[256];
    int t = threadIdx.x;
    double s = 0.0;
    for (int i = t; i < NBLK * 4; i += 256) s += partial[i];
    sh[t] = s;
    __syncthreads();
    for (int off = 128; off > 0; off >>= 1) {
        if (t < off) sh[t] += sh[t + off];
        __syncthreads();
    }
    if (t == 0)
        out[NSIG * EMB_DIM] = (float)(1.25 * sh[0] / (double)(NSIG * EMB_DIM));
}

extern "C" void kernel_launch(void* const* d_in, const int* in_sizes, int n_in,
                              void* d_out, int out_size, void* d_ws, size_t ws_size,
                              hipStream_t stream) {
    const float* z_e  = (const float*)d_in[0];
    const float* dict = (const float*)d_in[1];
    float* out = (float*)d_out;

    float*  Dn      = (float*)d_ws;
    float*  G       = (float*)((char*)d_ws + 65536);
    float*  DnT     = (float*)((char*)d_ws + 327680);
    double* partial = (double*)((char*)d_ws + 393216);

    norm_kernel<<<1, 256, 0, stream>>>(dict, Dn, DnT);
    gram_kernel<<<NUM_EMB, 256, 0, stream>>>(Dn, G);
    omp_kernel<<<NBLK, 256, 0, stream>>>(z_e, Dn, G, DnT, out, partial);
    loss_kernel<<<1, 256, 0, stream>>>(partial, out);
}